// Round 9
// baseline (390.789 us; speedup 1.0000x reference)
//
#include <hip/hip_runtime.h>

typedef short short8 __attribute__((ext_vector_type(8)));
typedef float floatx4 __attribute__((ext_vector_type(4)));

// ---------- bf16 helpers (raw ushort representation) ----------
__device__ __forceinline__ float b2f(unsigned int u16) {
    union { unsigned int i; float f; } v;
    v.i = u16 << 16;
    return v.f;
}
__device__ __forceinline__ unsigned short f2b(float f) {
    unsigned int i = __float_as_uint(f);
    unsigned int r = (i + 0x7FFFu + ((i >> 16) & 1u)) >> 16;  // RNE
    return (unsigned short)r;
}

#define N_WORD  50000
#define N_TOPIC 2000
#define N_DOC   50000
#define CHAIN_END   0xFFFFFFFFu
#define PAY_INVALID 0xFFFFFFFFu   // src<50000<0xFFFF so real pay never equals this
#define NB_GEMM 814   // 782 word blocks + 32 topic blocks
// All relations: H=4 sub-chains; head slot holds the FULL 8-byte first entry.
#define NSLOT_WW (N_WORD * 4)
#define NSLOT_WT (N_TOPIC * 4)
#define NSLOT_TT (N_TOPIC * 4)
#define NSLOT_WD (N_DOC * 4)
#define NSLOT_TD (N_DOC * 4)
#define NSLOT_ALL (NSLOT_WW + NSLOT_WT + NSLOT_TT + NSLOT_WD + NSLOT_TD)

// ---------------------------------------------------------------
// Input-dtype detection: flag=1 -> bf16 inputs, 0 -> f32 inputs.
// ---------------------------------------------------------------
__global__ void detect_kernel(const unsigned int* __restrict__ feat_u32,
                              unsigned int* __restrict__ flag)
{
    int cnt = 0;
    for (int i = 0; i < 256; ++i) {
        unsigned int u = feat_u32[i];
        int e = (u >> 7) & 0xFF;
        if (e >= 110 && e <= 140) ++cnt;
    }
    *flag = (cnt > 128) ? 1u : 0u;
}

// ---------------------------------------------------------------
// Weight swizzle -> B-fragment order for mfma_f32_16x16x32_bf16.
// ---------------------------------------------------------------
__global__ __launch_bounds__(256) void swizzle_kernel(
    const void* __restrict__ W0, const void* __restrict__ W1,
    const void* __restrict__ W2, const void* __restrict__ W3,
    const void* __restrict__ W4,
    const void* __restrict__ b0, const void* __restrict__ b1,
    const void* __restrict__ b2, const void* __restrict__ b3,
    const void* __restrict__ b4,
    short8* __restrict__ D0, short8* __restrict__ D1,
    short8* __restrict__ D2, short8* __restrict__ D3,
    short8* __restrict__ D4,
    unsigned short* __restrict__ bias_out,
    const unsigned int* __restrict__ flag_p)
{
    const int w = blockIdx.y;
    const void* W; const void* bs; short8* D; int S;
    switch (w) {
        case 0: W = W0; bs = b0; D = D0; S = 8; break;
        case 1: W = W1; bs = b1; D = D1; S = 8; break;
        case 2: W = W2; bs = b2; D = D2; S = 8; break;
        case 3: W = W3; bs = b3; D = D3; S = 4; break;
        default: W = W4; bs = b4; D = D4; S = 4; break;
    }
    const int n_entries = S * 8 * 64;
    const int mode = (int)*flag_p;
    for (int e = blockIdx.x * 256 + threadIdx.x; e < n_entries; e += 8 * 256) {
        const int lane = e & 63, t = (e >> 6) & 7, s = e >> 9;
        const int q = lane >> 4, n = t * 16 + (lane & 15);
        short8 val;
#pragma unroll
        for (int j = 0; j < 8; ++j) {
            const int k = s * 32 + q * 8 + j;
            unsigned short hv = mode ? ((const unsigned short*)W)[k * 128 + n]
                                     : f2b(((const float*)W)[k * 128 + n]);
            val[j] = (short)hv;
        }
        D[e] = val;
    }
    if (blockIdx.x == 0 && threadIdx.x < 128) {
        bias_out[w * 128 + threadIdx.x] =
            mode ? ((const unsigned short*)bs)[threadIdx.x]
                 : f2b(((const float*)bs)[threadIdx.x]);
    }
}

// ---------------------------------------------------------------
// MFMA GEMM body with LDS-staged B (32 KB halves). NO early return;
// OOB rows clamped on load, guarded on store.
// ---------------------------------------------------------------
template <int S, int NP>
__device__ __forceinline__ void gemm_body_lds(
    short8* __restrict__ Blds,          // 2048 entries = 32 KB
    const void* feat_, int n_rows, int bx,
    const short8* Ba, const short8* Bb, const short8* Bc,
    const unsigned short* bias_all, int ba, int bb, int bc,
    unsigned short* Oa, unsigned short* Ob, unsigned short* Oc,
    int mode_bf16)
{
    const int tid = threadIdx.x;
    const int lane = tid & 63;
    const int wave = tid >> 6;
    const int row0 = (bx * 4 + wave) * 16;
    const int m = lane & 15, q = lane >> 4;
    const int K = S * 32;
    int arow_idx = row0 + m;
    if (arow_idx >= n_rows) arow_idx = n_rows - 1;   // clamp (store guarded)

    short8 a[S];
    if (mode_bf16) {
        const short8* arow = (const short8*)((const unsigned short*)feat_ + (size_t)arow_idx * K);
#pragma unroll
        for (int s = 0; s < S; ++s) a[s] = arow[s * 4 + q];
    } else {
        const float* arow = (const float*)feat_ + (size_t)arow_idx * K;
#pragma unroll
        for (int s = 0; s < S; ++s) {
            const float4 f0 = ((const float4*)arow)[s * 8 + q * 2];
            const float4 f1 = ((const float4*)arow)[s * 8 + q * 2 + 1];
            short8 t;
            t[0] = (short)f2b(f0.x); t[1] = (short)f2b(f0.y);
            t[2] = (short)f2b(f0.z); t[3] = (short)f2b(f0.w);
            t[4] = (short)f2b(f1.x); t[5] = (short)f2b(f1.y);
            t[6] = (short)f2b(f1.z); t[7] = (short)f2b(f1.w);
            a[s] = t;
        }
    }

    constexpr int NH = (S * 8 * 64 > 2048) ? 2 : 1;   // halves of B
    constexpr int SH = S / NH;                         // K-slices per half

#pragma unroll
    for (int p = 0; p < NP; ++p) {
        const short8* B = (p == 0) ? Ba : ((p == 1) ? Bb : Bc);
        const unsigned short* bias = bias_all + ((p == 0) ? ba : ((p == 1) ? bb : bc)) * 128;
        unsigned short* O = (p == 0) ? Oa : ((p == 1) ? Ob : Oc);

        floatx4 acc[8];
#pragma unroll
        for (int t = 0; t < 8; ++t) { acc[t][0] = 0.f; acc[t][1] = 0.f; acc[t][2] = 0.f; acc[t][3] = 0.f; }

#pragma unroll
        for (int h = 0; h < NH; ++h) {
            __syncthreads();   // previous half/phase LDS reads complete
            for (int i = tid; i < SH * 8 * 64; i += 256) Blds[i] = B[h * (SH * 8 * 64) + i];
            __syncthreads();
#pragma unroll
            for (int s = 0; s < SH; ++s) {
#pragma unroll
                for (int t = 0; t < 8; ++t) {
                    short8 b = Blds[(s * 8 + t) * 64 + lane];
                    acc[t] = __builtin_amdgcn_mfma_f32_16x16x32_bf16(a[h * SH + s], b, acc[t], 0, 0, 0);
                }
            }
        }

#pragma unroll
        for (int t = 0; t < 8; ++t) {
            const float bb_ = b2f((unsigned int)bias[t * 16 + m]);
#pragma unroll
            for (int r = 0; r < 4; ++r) {
                const int row = row0 + q * 4 + r;
                if (row < n_rows)
                    O[(size_t)row * 128 + t * 16 + m] = f2b(acc[t][r] + bb_);
            }
        }
    }
}

// ---------------------------------------------------------------
// Link body: 8-byte heads hold the full first entry.
//   X = (i << 32) | pay;  old8 = atomicExch(&head8[slot], X);  ent[i] = old8
// ---------------------------------------------------------------
__device__ __forceinline__ void link_body(
    const int* __restrict__ src, const int* __restrict__ dst,
    const void* __restrict__ w_, int n, int i, int mode,
    unsigned long long* __restrict__ head8, unsigned long long* __restrict__ ent)
{
    if (i >= n) return;
    const int d = dst[i];
    const unsigned short w16 = mode ? ((const unsigned short*)w_)[i]
                                    : f2b(((const float*)w_)[i]);
    const unsigned int pay = ((unsigned int)w16 << 16) | (unsigned int)src[i];
    const unsigned long long X = ((unsigned long long)(unsigned int)i << 32)
                               | (unsigned long long)pay;
    const unsigned int slot = (unsigned int)d * 4 + ((unsigned int)i & 3);
    const unsigned long long old8 = atomicExch(&head8[slot], X);
    ent[i] = old8;
}

// ---------------------------------------------------------------
// Entry-based chain walks (predicated, one-step lookahead).
// ---------------------------------------------------------------
__device__ __forceinline__ void acc8(float a[8], const uint4& u, float w)
{
    a[0] += b2f(u.x & 0xffffu) * w; a[1] += b2f(u.x >> 16) * w;
    a[2] += b2f(u.y & 0xffffu) * w; a[3] += b2f(u.y >> 16) * w;
    a[4] += b2f(u.z & 0xffffu) * w; a[5] += b2f(u.z >> 16) * w;
    a[6] += b2f(u.w & 0xffffu) * w; a[7] += b2f(u.w >> 16) * w;
}
__device__ __forceinline__ uint4 rowld(const unsigned short* Wh, unsigned int pay, int sl)
{
    return ((const uint4*)(Wh + (size_t)(pay & 0xffffu) * 128))[sl];
}

__device__ __forceinline__ void walk1e(
    const unsigned long long* __restrict__ ent, const unsigned short* __restrict__ Wh,
    unsigned long long v, int sl, float a[8], float& cnt)
{
    while (true) {
        const unsigned int nx = (unsigned int)(v >> 32);
        const bool ln = (nx != CHAIN_END);
        unsigned long long vn = 0;
        if (ln) vn = ent[nx];                       // prefetch next entry
        const unsigned int pay = (unsigned int)v;
        if (pay != PAY_INVALID) {
            const uint4 u = rowld(Wh, pay, sl);
            acc8(a, u, b2f(pay >> 16));
            cnt += 1.0f;
        }
        if (!ln) break;
        v = vn;
    }
}

__device__ __forceinline__ void walk2e(
    const unsigned long long* __restrict__ ent1, const unsigned short* __restrict__ Wh1,
    unsigned long long v1,
    const unsigned long long* __restrict__ ent2, const unsigned short* __restrict__ Wh2,
    unsigned long long v2,
    int sl, float a1[8], float a2[8], float& c1, float& c2)
{
    bool l1 = true, l2 = true;
    while (l1 || l2) {
        const unsigned int n1 = (unsigned int)(v1 >> 32);
        const unsigned int n2 = (unsigned int)(v2 >> 32);
        const bool l1n = l1 && (n1 != CHAIN_END);
        const bool l2n = l2 && (n2 != CHAIN_END);
        unsigned long long v1n = 0, v2n = 0;
        if (l1n) v1n = ent1[n1];                    // prefetch next entries
        if (l2n) v2n = ent2[n2];
        const unsigned int p1 = (unsigned int)v1;
        const unsigned int p2 = (unsigned int)v2;
        const bool d1 = l1 && (p1 != PAY_INVALID);
        const bool d2 = l2 && (p2 != PAY_INVALID);
        uint4 u1, u2;
        if (d1) u1 = rowld(Wh1, p1, sl);
        if (d2) u2 = rowld(Wh2, p2, sl);
        if (d1) { acc8(a1, u1, b2f(p1 >> 16)); c1 += 1.0f; }
        if (d2) { acc8(a2, u2, b2f(p2 >> 16)); c2 += 1.0f; }
        v1 = v1n; v2 = v2n; l1 = l1n; l2 = l2n;
    }
}

__device__ __forceinline__ void write8(
    void* out, size_t off_elems, int node, int sl, const float r[8], int mode)
{
    if (mode) {
        uint4 o;
        o.x = (unsigned int)f2b(r[0]) | ((unsigned int)f2b(r[1]) << 16);
        o.y = (unsigned int)f2b(r[2]) | ((unsigned int)f2b(r[3]) << 16);
        o.z = (unsigned int)f2b(r[4]) | ((unsigned int)f2b(r[5]) << 16);
        o.w = (unsigned int)f2b(r[6]) | ((unsigned int)f2b(r[7]) << 16);
        *(uint4*)((unsigned short*)out + off_elems + (size_t)node * 128 + sl * 8) = o;
    } else {
        float* p = (float*)out + off_elems + (size_t)node * 128 + sl * 8;
        ((float4*)p)[0] = make_float4(r[0], r[1], r[2], r[3]);
        ((float4*)p)[1] = make_float4(r[4], r[5], r[6], r[7]);
    }
}

// Dual-relation mean body: 1 node/wave; group g walks (rel1 sub g, rel2 sub g).
__device__ __forceinline__ void dual_body(
    const unsigned long long* __restrict__ h1, const unsigned long long* __restrict__ e1t,
    const unsigned short* __restrict__ Wh1,
    const unsigned long long* __restrict__ h2, const unsigned long long* __restrict__ e2t,
    const unsigned short* __restrict__ Wh2,
    void* __restrict__ out, size_t off_elems, int blk, int mode)
{
    const int sl = threadIdx.x & 15;
    const int grp = (threadIdx.x >> 4) & 3;
    const int wave = threadIdx.x >> 6;
    const int node = blk * 4 + wave;
    float a1[8] = {0,0,0,0,0,0,0,0}, a2[8] = {0,0,0,0,0,0,0,0};
    float c1 = 0.f, c2 = 0.f;
    walk2e(e1t, Wh1, h1[node * 4 + grp], e2t, Wh2, h2[node * 4 + grp],
           sl, a1, a2, c1, c2);
#pragma unroll
    for (int j = 0; j < 8; ++j) {
        a1[j] += __shfl_xor(a1[j], 16); a1[j] += __shfl_xor(a1[j], 32);
        a2[j] += __shfl_xor(a2[j], 16); a2[j] += __shfl_xor(a2[j], 32);
    }
    c1 += __shfl_xor(c1, 16); c1 += __shfl_xor(c1, 32);
    c2 += __shfl_xor(c2, 16); c2 += __shfl_xor(c2, 32);
    const float i1 = (c1 > 0.f) ? 1.f / c1 : 0.f;
    const float i2 = (c2 > 0.f) ? 1.f / c2 : 0.f;
    float r[8];
#pragma unroll
    for (int j = 0; j < 8; ++j) r[j] = a1[j] * i1 + a2[j] * i2;
    if (grp == 0) write8(out, off_elems, node, sl, r, mode);
}

// ---------------------------------------------------------------
// K1: all GEMMs + link(wd, td).  GEMM traffic (stream reads + Wh
// writes + MFMA) overlaps the 900K-edge atomic write-wall.
// ---------------------------------------------------------------
__global__ __launch_bounds__(256) void gemm_linkdt_kernel(
    const void* __restrict__ feat_word, const void* __restrict__ feat_topic,
    const short8* __restrict__ Bww, const short8* __restrict__ Bwt,
    const short8* __restrict__ Bwd, const short8* __restrict__ Btt,
    const short8* __restrict__ Btd,
    const unsigned short* __restrict__ bias_all,
    unsigned short* __restrict__ Wh_ww, unsigned short* __restrict__ Wh_wt,
    unsigned short* __restrict__ Wh_wd, unsigned short* __restrict__ Wh_tt,
    unsigned short* __restrict__ Wh_td,
    const int* s3, const int* d3, const void* w3, int n3,
    unsigned long long* h3, unsigned long long* e3,
    const int* s4, const int* d4, const void* w4, int n4,
    unsigned long long* h4, unsigned long long* e4,
    const unsigned int* __restrict__ flag_p)
{
    __shared__ short8 Blds[2048];   // 32 KB
    const int mode = (int)*flag_p;

    if (blockIdx.x < NB_GEMM) {
        if (blockIdx.x < 782) {
            gemm_body_lds<8, 3>(Blds, feat_word, N_WORD, blockIdx.x, Bww, Bwt, Bwd,
                                bias_all, 0, 1, 2, Wh_ww, Wh_wt, Wh_wd, mode);
        } else {
            gemm_body_lds<4, 2>(Blds, feat_topic, N_TOPIC, blockIdx.x - 782, Btt, Btd,
                                (const short8*)nullptr, bias_all, 4, 3, 0,
                                Wh_tt, Wh_td, (unsigned short*)nullptr, mode);
        }
        return;
    }
    int lb = blockIdx.x - NB_GEMM;
    const int nb3 = (n3 + 255) >> 8;
    if (lb < nb3) { link_body(s3, d3, w3, n3, lb * 256 + threadIdx.x, mode, h3, e3); return; }
    lb -= nb3;
    link_body(s4, d4, w4, n4, lb * 256 + threadIdx.x, mode, h4, e4);
}

// ---------------------------------------------------------------
// K2: link(ww, wt, tt) INTERLEAVED with doc-gather (wd+td).
// Pattern period 11: 3 link blocks + 8 doc blocks, so the DRAM-write
// wall (link atomics) and the L3-random-read wall (doc rows) run
// concurrently on complementary resources for the whole kernel.
// ---------------------------------------------------------------
__global__ __launch_bounds__(256) void linkw_gatherdoc_kernel(
    const int* s0, const int* d0, const void* w0, int n0,
    unsigned long long* h0, unsigned long long* e0,
    const int* s1, const int* d1, const void* w1, int n1,
    unsigned long long* h1, unsigned long long* e1,
    const int* s2, const int* d2, const void* w2, int n2,
    unsigned long long* h2, unsigned long long* e2,
    const unsigned long long* __restrict__ h_wd, const unsigned long long* __restrict__ e_wd,
    const unsigned short* __restrict__ Wh_wd,
    const unsigned long long* __restrict__ h_td, const unsigned long long* __restrict__ e_td,
    const unsigned short* __restrict__ Wh_td,
    void* __restrict__ out,
    const unsigned int* __restrict__ flag_p)
{
    const int mode = (int)*flag_p;
    const int per = blockIdx.x / 11, r = blockIdx.x % 11;
    if (r < 3) {
        int lid = per * 3 + r;
        const int nb0 = (n0 + 255) >> 8, nb1 = (n1 + 255) >> 8, nb2 = (n2 + 255) >> 8;
        if (lid < nb0) { link_body(s0, d0, w0, n0, lid * 256 + threadIdx.x, mode, h0, e0); return; }
        lid -= nb0;
        if (lid < nb1) { link_body(s1, d1, w1, n1, lid * 256 + threadIdx.x, mode, h1, e1); return; }
        lid -= nb1;
        if (lid < nb2) { link_body(s2, d2, w2, n2, lid * 256 + threadIdx.x, mode, h2, e2); return; }
        return;
    }
    const int did = per * 8 + (r - 3);
    if (did >= 12500) return;
    dual_body(h_wd, e_wd, Wh_wd, h_td, e_td, Wh_td,
              out, (size_t)6656000, did, mode);
}

// ---------------------------------------------------------------
// K3: topic-gather (wt+tt) + word-gather (ww) in one kernel.
// Word overwrites the Wh_wd staging region (doc gather done in K2).
// ---------------------------------------------------------------
__global__ __launch_bounds__(256) void gather_tw_kernel(
    const unsigned long long* __restrict__ h_wt, const unsigned long long* __restrict__ e_wt,
    const unsigned short* __restrict__ Wh_wt,
    const unsigned long long* __restrict__ h_tt, const unsigned long long* __restrict__ e_tt,
    const unsigned short* __restrict__ Wh_tt,
    const unsigned long long* __restrict__ h_ww, const unsigned long long* __restrict__ e_ww,
    const unsigned short* __restrict__ Wh_ww,
    void* __restrict__ out,
    const unsigned int* __restrict__ flag_p)
{
    const int mode = (int)*flag_p;
    if (blockIdx.x < 500) {
        dual_body(h_wt, e_wt, Wh_wt, h_tt, e_tt, Wh_tt,
                  out, (size_t)6400000, blockIdx.x, mode);
        return;
    }
    const int sl = threadIdx.x & 15;
    const int grp = (threadIdx.x >> 4) & 3;
    const int wave = threadIdx.x >> 6;
    const int node = (blockIdx.x - 500) * 4 + wave;
    float a[8] = {0,0,0,0,0,0,0,0}; float cnt = 0.f;
    walk1e(e_ww, Wh_ww, h_ww[node * 4 + grp], sl, a, cnt);
#pragma unroll
    for (int j = 0; j < 8; ++j) { a[j] += __shfl_xor(a[j], 16); a[j] += __shfl_xor(a[j], 32); }
    cnt += __shfl_xor(cnt, 16); cnt += __shfl_xor(cnt, 32);
    const float inv = (cnt > 0.f) ? 1.f / cnt : 0.f;
    float r[8];
#pragma unroll
    for (int j = 0; j < 8; ++j) r[j] = a[j] * inv;
    if (grp == 0) write8(out, 0, node, sl, r, mode);
}

// ---------------------------------------------------------------
extern "C" void kernel_launch(void* const* d_in, const int* in_sizes, int n_in,
                              void* d_out, int out_size, void* d_ws, size_t ws_size,
                              hipStream_t stream)
{
    const void* feat_word  = d_in[0];
    const void* feat_topic = d_in[1];
    const int* ww_src = (const int*)d_in[2];
    const int* ww_dst = (const int*)d_in[3];
    const void* ww_w = d_in[4];
    const int* wt_src = (const int*)d_in[5];
    const int* wt_dst = (const int*)d_in[6];
    const void* wt_w = d_in[7];
    const int* wd_src = (const int*)d_in[8];
    const int* wd_dst = (const int*)d_in[9];
    const void* wd_w = d_in[10];
    const int* td_src = (const int*)d_in[11];
    const int* td_dst = (const int*)d_in[12];
    const void* td_w = d_in[13];
    const int* tt_src = (const int*)d_in[14];
    const int* tt_dst = (const int*)d_in[15];
    const void* tt_w = d_in[16];
    const void* W_ww = d_in[17];
    const void* b_ww = d_in[18];
    const void* W_wt = d_in[19];
    const void* b_wt = d_in[20];
    const void* W_wd = d_in[21];
    const void* b_wd = d_in[22];
    const void* W_td = d_in[23];
    const void* b_td = d_in[24];
    const void* W_tt = d_in[25];
    const void* b_tt = d_in[26];

    const int E_ww = in_sizes[2];
    const int E_wt = in_sizes[5];
    const int E_wd = in_sizes[8];
    const int E_td = in_sizes[11];
    const int E_tt = in_sizes[14];

    // ------------- workspace layout (~48.6 MB, proven-size range) ---------
    char* ws = (char*)d_ws;
    unsigned int* flag = (unsigned int*)ws;
    size_t off = 16;
    unsigned long long* h_ww = (unsigned long long*)(ws + off);   // 200,000 x 8B
    unsigned long long* h_wt = h_ww + NSLOT_WW;                   //   8,000
    unsigned long long* h_tt = h_wt + NSLOT_WT;                   //   8,000
    unsigned long long* h_wd = h_tt + NSLOT_TT;                   // 200,000
    unsigned long long* h_td = h_wd + NSLOT_WD;                   // 200,000
    off += (size_t)NSLOT_ALL * 8;
    off = (off + 15) & ~(size_t)15;
    short8* Bsw_ww = (short8*)(ws + off); off += 65536;
    short8* Bsw_wt = (short8*)(ws + off); off += 65536;
    short8* Bsw_wd = (short8*)(ws + off); off += 65536;
    short8* Bsw_td = (short8*)(ws + off); off += 32768;
    short8* Bsw_tt = (short8*)(ws + off); off += 32768;
    unsigned short* bias_all = (unsigned short*)(ws + off); off += 5 * 128 * 2;
    off = (off + 15) & ~(size_t)15;
    unsigned short* Wh_ww = (unsigned short*)(ws + off); off += (size_t)N_WORD * 128 * 2;
    unsigned short* Wh_wt = (unsigned short*)(ws + off); off += (size_t)N_WORD * 128 * 2;
    unsigned short* Wh_tt = (unsigned short*)(ws + off); off += (size_t)N_TOPIC * 128 * 2;
    unsigned short* Wh_td = (unsigned short*)(ws + off); off += (size_t)N_TOPIC * 128 * 2;
    off = (off + 7) & ~(size_t)7;
    unsigned long long* e_ww = (unsigned long long*)(ws + off); off += (size_t)E_ww * 8;
    unsigned long long* e_wt = (unsigned long long*)(ws + off); off += (size_t)E_wt * 8;
    unsigned long long* e_tt = (unsigned long long*)(ws + off); off += (size_t)E_tt * 8;
    unsigned long long* e_wd = (unsigned long long*)(ws + off); off += (size_t)E_wd * 8;
    unsigned long long* e_td = (unsigned long long*)(ws + off); off += (size_t)E_td * 8;

    // Wh_wd staged in d_out's word region (bf16, 12.8 MB); K2's doc gather
    // reads it, K3's word gather overwrites it last.
    unsigned short* Wh_wd = (unsigned short*)d_out;

    detect_kernel<<<1, 1, 0, stream>>>((const unsigned int*)feat_word, flag);
    hipMemsetAsync(h_ww, 0xFF, (size_t)NSLOT_ALL * 8, stream);   // sentinel entries

    swizzle_kernel<<<dim3(8, 5), 256, 0, stream>>>(
        W_ww, W_wt, W_wd, W_td, W_tt, b_ww, b_wt, b_wd, b_td, b_tt,
        Bsw_ww, Bsw_wt, Bsw_wd, Bsw_td, Bsw_tt, bias_all, flag);

    const int nb_ww = (E_ww + 255) / 256, nb_wt = (E_wt + 255) / 256,
              nb_tt = (E_tt + 255) / 256, nb_wd = (E_wd + 255) / 256,
              nb_td = (E_td + 255) / 256;

    // K1: all GEMMs + link(wd, td)
    gemm_linkdt_kernel<<<NB_GEMM + nb_wd + nb_td, 256, 0, stream>>>(
        feat_word, feat_topic, Bsw_ww, Bsw_wt, Bsw_wd, Bsw_tt, Bsw_td,
        bias_all, Wh_ww, Wh_wt, Wh_wd, Wh_tt, Wh_td,
        wd_src, wd_dst, wd_w, E_wd, h_wd, e_wd,
        td_src, td_dst, td_w, E_td, h_td, e_td, flag);

    // K2: link(ww, wt, tt) interleaved 3:8 with doc gather
    const int nlink2 = nb_ww + nb_wt + nb_tt;
    const int per_l = (nlink2 + 2) / 3, per_d = (12500 + 7) / 8;
    const int periods = (per_l > per_d) ? per_l : per_d;
    linkw_gatherdoc_kernel<<<periods * 11, 256, 0, stream>>>(
        ww_src, ww_dst, ww_w, E_ww, h_ww, e_ww,
        wt_src, wt_dst, wt_w, E_wt, h_wt, e_wt,
        tt_src, tt_dst, tt_w, E_tt, h_tt, e_tt,
        h_wd, e_wd, Wh_wd, h_td, e_td, Wh_td, d_out, flag);

    // K3: topic + word gather (word overwrites Wh_wd staging last)
    gather_tw_kernel<<<500 + 12500, 256, 0, stream>>>(
        h_wt, e_wt, Wh_wt, h_tt, e_tt, Wh_tt,
        h_ww, e_ww, Wh_ww, d_out, flag);
}

// Round 11
// 377.262 us; speedup vs baseline: 1.0359x; 1.0359x over previous
//
#include <hip/hip_runtime.h>

typedef short short8 __attribute__((ext_vector_type(8)));
typedef float floatx4 __attribute__((ext_vector_type(4)));

// ---------- bf16 helpers (raw ushort representation) ----------
__device__ __forceinline__ float b2f(unsigned int u16) {
    union { unsigned int i; float f; } v;
    v.i = u16 << 16;
    return v.f;
}
__device__ __forceinline__ unsigned short f2b(float f) {
    unsigned int i = __float_as_uint(f);
    unsigned int r = (i + 0x7FFFu + ((i >> 16) & 1u)) >> 16;  // RNE
    return (unsigned short)r;
}

#define N_WORD  50000
#define N_TOPIC 2000
#define N_DOC   50000
#define E_MAX   500000
#define CHAIN_END 0xFFFFFFFFu
#define NB_GEMM 814   // 782 word blocks + 32 topic blocks
// All relations use H=4 sub-chains per destination node.
#define NSLOT_WW 200000
#define NSLOT_WT 8000
#define NSLOT_TT 8000
#define NSLOT_WD 200000
#define NSLOT_TD 200000
#define NSLOT_ALL (NSLOT_WW + NSLOT_WT + NSLOT_TT + NSLOT_WD + NSLOT_TD)

// ---------------------------------------------------------------
// Input-dtype detection: flag=1 -> bf16 inputs, 0 -> f32 inputs.
// ---------------------------------------------------------------
__global__ void detect_kernel(const unsigned int* __restrict__ feat_u32,
                              unsigned int* __restrict__ flag)
{
    int cnt = 0;
    for (int i = 0; i < 256; ++i) {
        unsigned int u = feat_u32[i];
        int e = (u >> 7) & 0xFF;
        if (e >= 110 && e <= 140) ++cnt;
    }
    *flag = (cnt > 128) ? 1u : 0u;
}

// ---------------------------------------------------------------
// Weight swizzle -> B-fragment order for mfma_f32_16x16x32_bf16.
// ---------------------------------------------------------------
__global__ __launch_bounds__(256) void swizzle_kernel(
    const void* __restrict__ W0, const void* __restrict__ W1,
    const void* __restrict__ W2, const void* __restrict__ W3,
    const void* __restrict__ W4,
    const void* __restrict__ b0, const void* __restrict__ b1,
    const void* __restrict__ b2, const void* __restrict__ b3,
    const void* __restrict__ b4,
    short8* __restrict__ D0, short8* __restrict__ D1,
    short8* __restrict__ D2, short8* __restrict__ D3,
    short8* __restrict__ D4,
    unsigned short* __restrict__ bias_out,
    const unsigned int* __restrict__ flag_p)
{
    const int w = blockIdx.y;
    const void* W; const void* bs; short8* D; int S;
    switch (w) {
        case 0: W = W0; bs = b0; D = D0; S = 8; break;
        case 1: W = W1; bs = b1; D = D1; S = 8; break;
        case 2: W = W2; bs = b2; D = D2; S = 8; break;
        case 3: W = W3; bs = b3; D = D3; S = 4; break;
        default: W = W4; bs = b4; D = D4; S = 4; break;
    }
    const int n_entries = S * 8 * 64;
    const int mode = (int)*flag_p;
    for (int e = blockIdx.x * 256 + threadIdx.x; e < n_entries; e += 8 * 256) {
        const int lane = e & 63, t = (e >> 6) & 7, s = e >> 9;
        const int q = lane >> 4, n = t * 16 + (lane & 15);
        short8 val;
#pragma unroll
        for (int j = 0; j < 8; ++j) {
            const int k = s * 32 + q * 8 + j;
            unsigned short hv = mode ? ((const unsigned short*)W)[k * 128 + n]
                                     : f2b(((const float*)W)[k * 128 + n]);
            val[j] = (short)hv;
        }
        D[e] = val;
    }
    if (blockIdx.x == 0 && threadIdx.x < 128) {
        bias_out[w * 128 + threadIdx.x] =
            mode ? ((const unsigned short*)bs)[threadIdx.x]
                 : f2b(((const float*)bs)[threadIdx.x]);
    }
}

// ---------------------------------------------------------------
// MFMA GEMM body with LDS-staged B, staged in 32 KB halves so the
// fused kernel's link blocks can co-reside (4 blocks/CU at VGPR=128).
// NO early return (all waves must hit the barriers); OOB rows clamped
// on load, guarded on store.
// ---------------------------------------------------------------
template <int S, int NP>
__device__ __forceinline__ void gemm_body_lds(
    short8* __restrict__ Blds,          // 2048 entries = 32 KB
    const void* feat_, int n_rows, int bx,
    const short8* Ba, const short8* Bb, const short8* Bc,
    const unsigned short* bias_all, int ba, int bb, int bc,
    unsigned short* Oa, unsigned short* Ob, unsigned short* Oc,
    int mode_bf16)
{
    const int tid = threadIdx.x;
    const int lane = tid & 63;
    const int wave = tid >> 6;
    const int row0 = (bx * 4 + wave) * 16;
    const int m = lane & 15, q = lane >> 4;
    const int K = S * 32;
    int arow_idx = row0 + m;
    if (arow_idx >= n_rows) arow_idx = n_rows - 1;   // clamp (store guarded)

    short8 a[S];
    if (mode_bf16) {
        const short8* arow = (const short8*)((const unsigned short*)feat_ + (size_t)arow_idx * K);
#pragma unroll
        for (int s = 0; s < S; ++s) a[s] = arow[s * 4 + q];
    } else {
        const float* arow = (const float*)feat_ + (size_t)arow_idx * K;
#pragma unroll
        for (int s = 0; s < S; ++s) {
            const float4 f0 = ((const float4*)arow)[s * 8 + q * 2];
            const float4 f1 = ((const float4*)arow)[s * 8 + q * 2 + 1];
            short8 t;
            t[0] = (short)f2b(f0.x); t[1] = (short)f2b(f0.y);
            t[2] = (short)f2b(f0.z); t[3] = (short)f2b(f0.w);
            t[4] = (short)f2b(f1.x); t[5] = (short)f2b(f1.y);
            t[6] = (short)f2b(f1.z); t[7] = (short)f2b(f1.w);
            a[s] = t;
        }
    }

    constexpr int NH = (S * 8 * 64 > 2048) ? 2 : 1;   // halves of B
    constexpr int SH = S / NH;                         // K-slices per half

#pragma unroll
    for (int p = 0; p < NP; ++p) {
        const short8* B = (p == 0) ? Ba : ((p == 1) ? Bb : Bc);
        const unsigned short* bias = bias_all + ((p == 0) ? ba : ((p == 1) ? bb : bc)) * 128;
        unsigned short* O = (p == 0) ? Oa : ((p == 1) ? Ob : Oc);

        floatx4 acc[8];
#pragma unroll
        for (int t = 0; t < 8; ++t) { acc[t][0] = 0.f; acc[t][1] = 0.f; acc[t][2] = 0.f; acc[t][3] = 0.f; }

#pragma unroll
        for (int h = 0; h < NH; ++h) {
            __syncthreads();   // previous half/phase LDS reads complete
            // stage 32 KB half of B into LDS (coalesced 16 B/lane)
            for (int i = tid; i < SH * 8 * 64; i += 256) Blds[i] = B[h * (SH * 8 * 64) + i];
            __syncthreads();
#pragma unroll
            for (int s = 0; s < SH; ++s) {
#pragma unroll
                for (int t = 0; t < 8; ++t) {
                    short8 b = Blds[(s * 8 + t) * 64 + lane];
                    acc[t] = __builtin_amdgcn_mfma_f32_16x16x32_bf16(a[h * SH + s], b, acc[t], 0, 0, 0);
                }
            }
        }

#pragma unroll
        for (int t = 0; t < 8; ++t) {
            const float bb_ = b2f((unsigned int)bias[t * 16 + m]);
#pragma unroll
            for (int r = 0; r < 4; ++r) {
                const int row = row0 + q * 4 + r;
                if (row < n_rows)
                    O[(size_t)row * 128 + t * 16 + m] = f2b(acc[t][r] + bb_);
            }
        }
    }
}

// ---------------------------------------------------------------
// FUSED link + gemm kernel (gemm blocks first, link blocks after;
// 1 edge/thread — proven shape, VGPR=128).
// Link: per edge i,  slot = dst*4 + (i & 3);
//   old = atomicExch(&head[slot], i);
//   ent[i] = (old << 32) | (w_bf16 << 16) | src
// ---------------------------------------------------------------
__global__ __launch_bounds__(256) void link_gemm_kernel(
    // gemm
    const void* __restrict__ feat_word, const void* __restrict__ feat_topic,
    const short8* __restrict__ Bww, const short8* __restrict__ Bwt,
    const short8* __restrict__ Bwd, const short8* __restrict__ Btt,
    const short8* __restrict__ Btd,
    const unsigned short* __restrict__ bias_all,
    unsigned short* __restrict__ Wh_ww, unsigned short* __restrict__ Wh_wt,
    unsigned short* __restrict__ Wh_wd, unsigned short* __restrict__ Wh_tt,
    unsigned short* __restrict__ Wh_td,
    // link (relation order: ww, wt, tt, wd, td — all H=4)
    const int* s0, const int* d0, const void* w0, int n0, unsigned int* h0, unsigned long long* e0,
    const int* s1, const int* d1, const void* w1, int n1, unsigned int* h1, unsigned long long* e1,
    const int* s2, const int* d2, const void* w2, int n2, unsigned int* h2, unsigned long long* e2,
    const int* s3, const int* d3, const void* w3, int n3, unsigned int* h3, unsigned long long* e3,
    const int* s4, const int* d4, const void* w4, int n4, unsigned int* h4, unsigned long long* e4,
    const unsigned int* __restrict__ flag_p)
{
    __shared__ short8 Blds[2048];   // 32 KB
    const int mode = (int)*flag_p;

    if (blockIdx.x < NB_GEMM) {
        if (blockIdx.x < 782) {
            gemm_body_lds<8, 3>(Blds, feat_word, N_WORD, blockIdx.x, Bww, Bwt, Bwd,
                                bias_all, 0, 1, 2, Wh_ww, Wh_wt, Wh_wd, mode);
        } else {
            gemm_body_lds<4, 2>(Blds, feat_topic, N_TOPIC, blockIdx.x - 782, Btt, Btd,
                                (const short8*)nullptr, bias_all, 4, 3, 0,
                                Wh_tt, Wh_td, (unsigned short*)nullptr, mode);
        }
        return;
    }

    // ------------- link path -------------
    int lb = blockIdx.x - NB_GEMM;
    const int nb0 = (n0 + 255) >> 8, nb1 = (n1 + 255) >> 8, nb2 = (n2 + 255) >> 8,
              nb3 = (n3 + 255) >> 8;
    const int* src; const int* dst; const void* w_; int n;
    unsigned int* head; unsigned long long* ent;
    if (lb < nb0)      { src = s0; dst = d0; w_ = w0; n = n0; head = h0; ent = e0; }
    else if ((lb -= nb0) < nb1) { src = s1; dst = d1; w_ = w1; n = n1; head = h1; ent = e1; }
    else if ((lb -= nb1) < nb2) { src = s2; dst = d2; w_ = w2; n = n2; head = h2; ent = e2; }
    else if ((lb -= nb2) < nb3) { src = s3; dst = d3; w_ = w3; n = n3; head = h3; ent = e3; }
    else { lb -= nb3;  src = s4; dst = d4; w_ = w4; n = n4; head = h4; ent = e4; }

    const int i = lb * 256 + threadIdx.x;
    if (i >= n) return;
    const int d = dst[i];
    const unsigned int slot = (unsigned int)d * 4 + ((unsigned int)i & 3);
    const unsigned int old = atomicExch(&head[slot], (unsigned int)i);
    const unsigned short w16 = mode ? ((const unsigned short*)w_)[i]
                                    : f2b(((const float*)w_)[i]);
    ent[i] = ((unsigned long long)old << 32)
           | ((unsigned long long)w16 << 16)
           | (unsigned long long)(unsigned int)src[i];
}

// ---------------------------------------------------------------
// Chain walks with one-step LOOKAHEAD: the next ent[] pointer load is
// issued concurrently with the current Wh row load, so per-step latency
// ~= max(lat_ent, lat_row) instead of the sum.  e is uniform across the
// 16-lane group (sl selects the 16 B slice of the 256 B row).
// Dummy clamped loads (index 0) when a chain is exhausted are valid
// in-workspace reads whose results are discarded.
// ---------------------------------------------------------------
__device__ __forceinline__ void acc8(float a[8], const uint4& u, float w)
{
    a[0] += b2f(u.x & 0xffffu) * w; a[1] += b2f(u.x >> 16) * w;
    a[2] += b2f(u.y & 0xffffu) * w; a[3] += b2f(u.y >> 16) * w;
    a[4] += b2f(u.z & 0xffffu) * w; a[5] += b2f(u.z >> 16) * w;
    a[6] += b2f(u.w & 0xffffu) * w; a[7] += b2f(u.w >> 16) * w;
}

// single chain, lookahead
__device__ __forceinline__ void walk1(
    const unsigned long long* __restrict__ ent,
    const unsigned short* __restrict__ Wh,
    unsigned int e, int sl, float a[8], float& cnt)
{
    bool live = (e != CHAIN_END);
    unsigned long long v = ent[live ? e : 0];
    while (live) {
        const unsigned int nx = (unsigned int)(v >> 32);
        const bool live_n = (nx != CHAIN_END);
        const unsigned long long vn = ent[live_n ? nx : 0];          // prefetch next
        const uint4 u = ((const uint4*)(Wh + (size_t)((unsigned int)v & 0xffffu) * 128))[sl];
        acc8(a, u, b2f(((unsigned int)v) >> 16));
        cnt += 1.0f;
        v = vn; live = live_n;
    }
}

// two independent chains (different relations), interleaved + lookahead
__device__ __forceinline__ void walk2(
    const unsigned long long* __restrict__ ent1, const unsigned short* __restrict__ Wh1, unsigned int e1,
    const unsigned long long* __restrict__ ent2, const unsigned short* __restrict__ Wh2, unsigned int e2,
    int sl, float a1[8], float a2[8], float& c1, float& c2)
{
    bool l1 = (e1 != CHAIN_END), l2 = (e2 != CHAIN_END);
    unsigned long long v1 = ent1[l1 ? e1 : 0];
    unsigned long long v2 = ent2[l2 ? e2 : 0];
    while (l1 || l2) {
        const unsigned int n1 = (unsigned int)(v1 >> 32);
        const unsigned int n2 = (unsigned int)(v2 >> 32);
        const bool l1n = l1 && (n1 != CHAIN_END);
        const bool l2n = l2 && (n2 != CHAIN_END);
        const unsigned long long v1n = ent1[l1n ? n1 : 0];           // prefetch next
        const unsigned long long v2n = ent2[l2n ? n2 : 0];
        const uint4 u1 = ((const uint4*)(Wh1 + (size_t)((unsigned int)v1 & 0xffffu) * 128))[sl];
        const uint4 u2 = ((const uint4*)(Wh2 + (size_t)((unsigned int)v2 & 0xffffu) * 128))[sl];
        if (l1) { acc8(a1, u1, b2f(((unsigned int)v1) >> 16)); c1 += 1.0f; }
        if (l2) { acc8(a2, u2, b2f(((unsigned int)v2) >> 16)); c2 += 1.0f; }
        v1 = v1n; v2 = v2n; l1 = l1n; l2 = l2n;
    }
}

__device__ __forceinline__ void write8(
    void* out, size_t off_elems, int node, int sl, const float r[8], int mode)
{
    if (mode) {
        uint4 o;
        o.x = (unsigned int)f2b(r[0]) | ((unsigned int)f2b(r[1]) << 16);
        o.y = (unsigned int)f2b(r[2]) | ((unsigned int)f2b(r[3]) << 16);
        o.z = (unsigned int)f2b(r[4]) | ((unsigned int)f2b(r[5]) << 16);
        o.w = (unsigned int)f2b(r[6]) | ((unsigned int)f2b(r[7]) << 16);
        *(uint4*)((unsigned short*)out + off_elems + (size_t)node * 128 + sl * 8) = o;
    } else {
        float* p = (float*)out + off_elems + (size_t)node * 128 + sl * 8;
        ((float4*)p)[0] = make_float4(r[0], r[1], r[2], r[3]);
        ((float4*)p)[1] = make_float4(r[4], r[5], r[6], r[7]);
    }
}

// ---------------------------------------------------------------
// Dual-relation mean body: 1 wave per node, 4 sub-chains per relation
// walked by the 4 16-lane groups (walk2 -> 2 chase states per group),
// shfl-reduce across groups, r = a1/deg1 + a2/deg2.
// Used for topic (wt+tt) and doc (wd+td).
// ---------------------------------------------------------------
__device__ __forceinline__ void dual_body(
    const unsigned int* __restrict__ h1, const unsigned long long* __restrict__ e1t,
    const unsigned short* __restrict__ Wh1,
    const unsigned int* __restrict__ h2, const unsigned long long* __restrict__ e2t,
    const unsigned short* __restrict__ Wh2,
    void* __restrict__ out, size_t off_elems, int blk, int mode)
{
    const int sl = threadIdx.x & 15;
    const int grp = (threadIdx.x >> 4) & 3;
    const int wave = threadIdx.x >> 6;
    const int node = blk * 4 + wave;
    float a1[8] = {0,0,0,0,0,0,0,0}, a2[8] = {0,0,0,0,0,0,0,0};
    float c1 = 0.f, c2 = 0.f;
    walk2(e1t, Wh1, h1[node * 4 + grp], e2t, Wh2, h2[node * 4 + grp],
          sl, a1, a2, c1, c2);
#pragma unroll
    for (int j = 0; j < 8; ++j) {
        a1[j] += __shfl_xor(a1[j], 16); a1[j] += __shfl_xor(a1[j], 32);
        a2[j] += __shfl_xor(a2[j], 16); a2[j] += __shfl_xor(a2[j], 32);
    }
    c1 += __shfl_xor(c1, 16); c1 += __shfl_xor(c1, 32);
    c2 += __shfl_xor(c2, 16); c2 += __shfl_xor(c2, 32);
    const float i1 = (c1 > 0.f) ? 1.f / c1 : 0.f;
    const float i2 = (c2 > 0.f) ? 1.f / c2 : 0.f;
    float r[8];
#pragma unroll
    for (int j = 0; j < 8; ++j) r[j] = a1[j] * i1 + a2[j] * i2;
    if (grp == 0) write8(out, off_elems, node, sl, r, mode);
}

// word: single relation (ww), 4 sub-chains via groups, lookahead walk
__device__ __forceinline__ void word_body(
    const unsigned int* __restrict__ h_ww, const unsigned long long* __restrict__ e_ww,
    const unsigned short* __restrict__ Wh_ww,
    void* __restrict__ out, int blk, int mode)
{
    const int sl = threadIdx.x & 15;
    const int grp = (threadIdx.x >> 4) & 3;
    const int wave = threadIdx.x >> 6;
    const int node = blk * 4 + wave;
    float a[8] = {0,0,0,0,0,0,0,0}; float cnt = 0.f;
    walk1(e_ww, Wh_ww, h_ww[node * 4 + grp], sl, a, cnt);
#pragma unroll
    for (int j = 0; j < 8; ++j) { a[j] += __shfl_xor(a[j], 16); a[j] += __shfl_xor(a[j], 32); }
    cnt += __shfl_xor(cnt, 16); cnt += __shfl_xor(cnt, 32);
    const float inv = (cnt > 0.f) ? 1.f / cnt : 0.f;
    float r[8];
#pragma unroll
    for (int j = 0; j < 8; ++j) r[j] = a[j] * inv;
    if (grp == 0) write8(out, 0, node, sl, r, mode);
}

// ---------------------------------------------------------------
// Gather kernel 1: blocks [0,500) topic, [500,13000) doc.
// Doc reads Wh_wd staged in d_out's word region; topic work hides
// inside the doc dispatch (no serial exposure).
// ---------------------------------------------------------------
__global__ __launch_bounds__(256) void gather_dt_kernel(
    const unsigned int* __restrict__ h_wt, const unsigned long long* __restrict__ e_wt,
    const unsigned short* __restrict__ Wh_wt,
    const unsigned int* __restrict__ h_tt, const unsigned long long* __restrict__ e_tt,
    const unsigned short* __restrict__ Wh_tt,
    const unsigned int* __restrict__ h_wd, const unsigned long long* __restrict__ e_wd,
    const unsigned short* __restrict__ Wh_wd,
    const unsigned int* __restrict__ h_td, const unsigned long long* __restrict__ e_td,
    const unsigned short* __restrict__ Wh_td,
    void* __restrict__ out,
    const unsigned int* __restrict__ flag_p)
{
    const int mode = (int)*flag_p;
    if (blockIdx.x < 500) {
        dual_body(h_wt, e_wt, Wh_wt, h_tt, e_tt, Wh_tt,
                  out, (size_t)6400000, blockIdx.x, mode);
    } else {
        dual_body(h_wd, e_wd, Wh_wd, h_td, e_td, Wh_td,
                  out, (size_t)6656000, blockIdx.x - 500, mode);
    }
}

// ---------------------------------------------------------------
// Gather kernel 2: word (runs last; overwrites Wh_wd staging region).
// ---------------------------------------------------------------
__global__ __launch_bounds__(256) void gather_w_kernel(
    const unsigned int* __restrict__ h_ww, const unsigned long long* __restrict__ e_ww,
    const unsigned short* __restrict__ Wh_ww,
    void* __restrict__ out,
    const unsigned int* __restrict__ flag_p)
{
    word_body(h_ww, e_ww, Wh_ww, out, blockIdx.x, (int)*flag_p);
}

// ---------------------------------------------------------------
extern "C" void kernel_launch(void* const* d_in, const int* in_sizes, int n_in,
                              void* d_out, int out_size, void* d_ws, size_t ws_size,
                              hipStream_t stream)
{
    const void* feat_word  = d_in[0];
    const void* feat_topic = d_in[1];
    const int* ww_src = (const int*)d_in[2];
    const int* ww_dst = (const int*)d_in[3];
    const void* ww_w = d_in[4];
    const int* wt_src = (const int*)d_in[5];
    const int* wt_dst = (const int*)d_in[6];
    const void* wt_w = d_in[7];
    const int* wd_src = (const int*)d_in[8];
    const int* wd_dst = (const int*)d_in[9];
    const void* wd_w = d_in[10];
    const int* td_src = (const int*)d_in[11];
    const int* td_dst = (const int*)d_in[12];
    const void* td_w = d_in[13];
    const int* tt_src = (const int*)d_in[14];
    const int* tt_dst = (const int*)d_in[15];
    const void* tt_w = d_in[16];
    const void* W_ww = d_in[17];
    const void* b_ww = d_in[18];
    const void* W_wt = d_in[19];
    const void* b_wt = d_in[20];
    const void* W_wd = d_in[21];
    const void* b_wd = d_in[22];
    const void* W_td = d_in[23];
    const void* b_td = d_in[24];
    const void* W_tt = d_in[25];
    const void* b_tt = d_in[26];

    const int E_ww = in_sizes[2];
    const int E_wt = in_sizes[5];
    const int E_wd = in_sizes[8];
    const int E_td = in_sizes[11];
    const int E_tt = in_sizes[14];

    // ---------------- workspace layout (~50 MB) ----------------
    char* ws = (char*)d_ws;
    unsigned int* flag = (unsigned int*)ws;
    unsigned int* head_base = (unsigned int*)(ws + 4);
    unsigned int* h_ww = head_base;                              // 200,000 (H=4)
    unsigned int* h_wt = h_ww + NSLOT_WW;                        //   8,000 (H=4)
    unsigned int* h_tt = h_wt + NSLOT_WT;                        //   8,000 (H=4)
    unsigned int* h_wd = h_tt + NSLOT_TT;                        // 200,000 (H=4)
    unsigned int* h_td = h_wd + NSLOT_WD;                        // 200,000 (H=4)
    size_t off = 4 + (size_t)NSLOT_ALL * 4;
    off = (off + 15) & ~(size_t)15;
    short8* Bsw_ww = (short8*)(ws + off); off += 65536;
    short8* Bsw_wt = (short8*)(ws + off); off += 65536;
    short8* Bsw_wd = (short8*)(ws + off); off += 65536;
    short8* Bsw_td = (short8*)(ws + off); off += 32768;
    short8* Bsw_tt = (short8*)(ws + off); off += 32768;
    unsigned short* bias_all = (unsigned short*)(ws + off); off += 5 * 128 * 2;
    off = (off + 15) & ~(size_t)15;
    unsigned short* Wh_ww = (unsigned short*)(ws + off); off += (size_t)N_WORD * 128 * 2;
    unsigned short* Wh_wt = (unsigned short*)(ws + off); off += (size_t)N_WORD * 128 * 2;
    unsigned short* Wh_tt = (unsigned short*)(ws + off); off += (size_t)N_TOPIC * 128 * 2;
    unsigned short* Wh_td = (unsigned short*)(ws + off); off += (size_t)N_TOPIC * 128 * 2;
    off = (off + 7) & ~(size_t)7;
    unsigned long long* e_ww = (unsigned long long*)(ws + off); off += (size_t)E_MAX * 8;
    unsigned long long* e_wt = (unsigned long long*)(ws + off); off += (size_t)E_MAX * 8;
    unsigned long long* e_tt = (unsigned long long*)(ws + off); off += (size_t)E_MAX * 8;
    unsigned long long* e_wd = (unsigned long long*)(ws + off); off += (size_t)E_MAX * 8;
    unsigned long long* e_td = (unsigned long long*)(ws + off); off += (size_t)E_MAX * 8;

    // Wh_wd staged in d_out's word region (12.8 MB); gather_dt reads it,
    // gather_w overwrites it last.
    unsigned short* Wh_wd = (unsigned short*)d_out;

    detect_kernel<<<1, 1, 0, stream>>>((const unsigned int*)feat_word, flag);
    hipMemsetAsync(head_base, 0xFF, (size_t)NSLOT_ALL * 4, stream);   // chain ends

    swizzle_kernel<<<dim3(8, 5), 256, 0, stream>>>(
        W_ww, W_wt, W_wd, W_td, W_tt, b_ww, b_wt, b_wd, b_td, b_tt,
        Bsw_ww, Bsw_wt, Bsw_wd, Bsw_td, Bsw_tt, bias_all, flag);

    // fused link + gemm: independent work, complementary pipes
    const int nb_link = ((E_ww + 255) / 256) + ((E_wt + 255) / 256) +
                        ((E_tt + 255) / 256) + ((E_wd + 255) / 256) +
                        ((E_td + 255) / 256);
    link_gemm_kernel<<<NB_GEMM + nb_link, 256, 0, stream>>>(
        feat_word, feat_topic, Bsw_ww, Bsw_wt, Bsw_wd, Bsw_tt, Bsw_td,
        bias_all, Wh_ww, Wh_wt, Wh_wd, Wh_tt, Wh_td,
        ww_src, ww_dst, ww_w, E_ww, h_ww, e_ww,
        wt_src, wt_dst, wt_w, E_wt, h_wt, e_wt,
        tt_src, tt_dst, tt_w, E_tt, h_tt, e_tt,
        wd_src, wd_dst, wd_w, E_wd, h_wd, e_wd,
        td_src, td_dst, td_w, E_td, h_td, e_td, flag);

    // topic+doc gather (topic hides inside the doc dispatch)
    gather_dt_kernel<<<500 + 12500, 256, 0, stream>>>(
        h_wt, e_wt, Wh_wt, h_tt, e_tt, Wh_tt,
        h_wd, e_wd, Wh_wd, h_td, e_td, Wh_td, d_out, flag);

    // word gather (overwrites the Wh_wd staging region last)
    gather_w_kernel<<<12500, 256, 0, stream>>>(
        h_ww, e_ww, Wh_ww, d_out, flag);
}